// Round 1
// 462.212 us; speedup vs baseline: 1.0268x; 1.0268x over previous
//
#include <hip/hip_runtime.h>
#include <hip/hip_bf16.h>
#include <stdint.h>

#define I_SIZE 256
#define D_DIM 128
#define BATCH 1024

typedef __attribute__((ext_vector_type(8))) short short8;
typedef __attribute__((ext_vector_type(4))) short short4v;
typedef __attribute__((ext_vector_type(4))) float floatx4;

__device__ inline short f2bf(float f) {
    union { float f; uint32_t u; } v; v.f = f;
    uint32_t u = v.u;
    uint32_t r = (u + 0x7FFFu + ((u >> 16) & 1u)) >> 16;   // RNE
    return (short)(r & 0xFFFFu);
}
__device__ inline float bf2f(short s) {
    union { uint32_t u; float f; } v; v.u = ((uint32_t)(uint16_t)s) << 16;
    return v.f;
}
__device__ inline uint32_t pkbf(float a, float b) {
    __hip_bfloat162 h = __float22bfloat162_rn(make_float2(a, b));
    union { __hip_bfloat162 h; uint32_t u; } v; v.h = h; return v.u;
}
__device__ inline float sigmoidf_fast(float x) { return 1.0f / (1.0f + __expf(-x)); }
__device__ inline float tanhf_fast(float x)    { return 2.0f / (1.0f + __expf(-2.0f * x)) - 1.0f; }

// ============================================================================
// Fully fused kernel: 256 blocks (1 per group, 1 per CU), 1024 threads
// (16 waves, 4/SIMD). NO workspace use at all — the U fp32->bf16 transpose
// is done once per block in the prologue, writing the XOR-swizzled LDS image
// (element j of U^T row n=k at k*128 + p*8 + (j&7), p=(j>>3)^(k&7)) that the
// B-fragment reads (pswz) expect. Amortized over 8 passes of 128 batch rows.
// ============================================================================
#define S_H 136   // hgb stride in shorts: rows 16B-aligned, A-frag b128 conflict-free

__global__ __launch_bounds__(1024, 4) void gru_fused(
    const float* __restrict__ X, const float* __restrict__ H,
    const float* __restrict__ Wr, const float* __restrict__ Wz, const float* __restrict__ Wh,
    const float* __restrict__ Ur, const float* __restrict__ Uz, const float* __restrict__ Uh,
    const float* __restrict__ br, const float* __restrict__ bz, const float* __restrict__ bh,
    float* __restrict__ out)
{
    __shared__ short Ut[3 * D_DIM * D_DIM];   // 98304 B swizzled bf16 U^T (r,z,h)
    __shared__ short hgb[D_DIM * S_H];        // 34816 B hg tile (later p = r*hg)
    __shared__ float Wl[6][D_DIM];            // 3072 B

    const int tid   = threadIdx.x;
    const int group = blockIdx.x;
    const int lane  = tid & 63;
    const int w     = tid >> 6;

    if (tid < D_DIM) {
        Wl[0][tid] = Wr[group * D_DIM + tid];
        Wl[1][tid] = Wz[group * D_DIM + tid];
        Wl[2][tid] = Wh[group * D_DIM + tid];
        Wl[3][tid] = br[group * D_DIM + tid];
        Wl[4][tid] = bz[group * D_DIM + tid];
        Wl[5][tid] = bh[group * D_DIM + tid];
    }

    // ---- fused U transpose: global fp32 (coalesced row reads) -> LDS bf16,
    //      transposed + XOR-swizzled. 196 KB/block, once. ----
    {
        const int kc = tid & 127;          // column k of U (contig across lanes)
        const int jb = tid >> 7;           // 0..7
        #pragma unroll
        for (int g = 0; g < 3; ++g) {
            const float* Ug = ((g == 0) ? Ur : (g == 1) ? Uz : Uh)
                              + (size_t)group * (D_DIM * D_DIM);
            short* dst = &Ut[g * (D_DIM * D_DIM)];
            #pragma unroll
            for (int m = 0; m < 4; ++m) {
                const int j0 = m * 8 + jb;                  // 0..31 (j-quad)
                float a0 = Ug[(4 * j0 + 0) * D_DIM + kc];
                float a1 = Ug[(4 * j0 + 1) * D_DIM + kc];
                float a2 = Ug[(4 * j0 + 2) * D_DIM + kc];
                float a3 = Ug[(4 * j0 + 3) * D_DIM + kc];
                short4v s; s.x = f2bf(a0); s.y = f2bf(a1); s.z = f2bf(a2); s.w = f2bf(a3);
                const int p = (j0 >> 1) ^ (kc & 7);
                *(short4v*)&dst[kc * D_DIM + p * 8 + 4 * (j0 & 1)] = s;  // b64 write
            }
        }
    }
    // No barrier here: the first loop-top __syncthreads (after hg staging,
    // which touches only hgb) also orders the Ut and Wl writes.

    const int am = lane & 15;
    const int aq = lane >> 4;
    const int rg = w >> 1;           // row group 0..7
    const int nh = w & 1;            // n-half
    const int r0 = rg * 16;
    const size_t HOFF = (size_t)BATCH * I_SIZE * D_DIM;
    const int srow = tid >> 3;           // staging row 0..127
    const int scol = (tid & 7) * 4;      // staging col base

    int pswz[4];
    #pragma unroll
    for (int kk = 0; kk < 4; ++kk) pswz[kk] = ((4 * kk + aq) ^ (am & 7)) * 8;

    const floatx4 zero = {0.f, 0.f, 0.f, 0.f};

    for (int pass = 0; pass < 8; ++pass) {
        const int R = pass * 128;

        // ---- stage hg rows -> LDS bf16 (coalesced 128B/row-octet loads) ----
        #pragma unroll
        for (int it = 0; it < 4; ++it) {
            int col = scol + it * 32;
            float4 v = *(const float4*)(H + (size_t)(R + srow) * (I_SIZE * D_DIM)
                                        + group * D_DIM + col);
            uint2 uu; uu.x = pkbf(v.x, v.y); uu.y = pkbf(v.z, v.w);
            *(uint2*)&hgb[srow * S_H + col] = uu;
        }
        __syncthreads();

        // ---- A fragments (hg) ----
        short8 a[4];
        #pragma unroll
        for (int kk = 0; kk < 4; ++kk)
            a[kk] = *(const short8*)&hgb[(r0 + am) * S_H + kk * 32 + aq * 8];

        // ---- r and z GEMMs (this wave's 64-col half) ----
        floatx4 accr[4], accz[4];
        #pragma unroll
        for (int t2 = 0; t2 < 4; ++t2) { accr[t2] = zero; accz[t2] = zero; }

        #pragma unroll
        for (int t2 = 0; t2 < 4; ++t2) {
            const int n = nh * 64 + t2 * 16 + am;
            const short* rowp = &Ut[n * D_DIM];
            #pragma unroll
            for (int kk = 0; kk < 4; ++kk)
                accr[t2] = __builtin_amdgcn_mfma_f32_16x16x32_bf16(
                    a[kk], *(const short8*)(rowp + pswz[kk]), accr[t2], 0, 0, 0);
            #pragma unroll
            for (int kk = 0; kk < 4; ++kk)
                accz[t2] = __builtin_amdgcn_mfma_f32_16x16x32_bf16(
                    a[kk], *(const short8*)(rowp + 16384 + pswz[kk]), accz[t2], 0, 0, 0);
        }

        // ---- epilogue 1: r,z gates; p = r*hg in place ----
        float Xv[4];
        #pragma unroll
        for (int pp = 0; pp < 4; ++pp)
            Xv[pp] = X[(size_t)(R + r0 + aq * 4 + pp) * I_SIZE + group];

        float zr[4][4], hgc[4][4];
        #pragma unroll
        for (int t2 = 0; t2 < 4; ++t2) {
            const int c = nh * 64 + t2 * 16 + am;
            const float wr = Wl[0][c], wz = Wl[1][c], brv = Wl[3][c], bzv = Wl[4][c];
            #pragma unroll
            for (int pp = 0; pp < 4; ++pp) {
                const int rl = r0 + aq * 4 + pp;
                float hgv = bf2f(hgb[rl * S_H + c]);
                float rv = sigmoidf_fast(accr[t2][pp] + Xv[pp] * wr + brv);
                float zv = sigmoidf_fast(accz[t2][pp] + Xv[pp] * wz + bzv);
                zr[t2][pp]  = zv;
                hgc[t2][pp] = hgv;
                hgb[rl * S_H + c] = f2bf(rv * hgv);
            }
        }
        __syncthreads();

        // ---- h GEMM: A = p = r*hg ----
        short8 ap[4];
        #pragma unroll
        for (int kk = 0; kk < 4; ++kk)
            ap[kk] = *(const short8*)&hgb[(r0 + am) * S_H + kk * 32 + aq * 8];

        floatx4 acch[4];
        #pragma unroll
        for (int t2 = 0; t2 < 4; ++t2) acch[t2] = zero;
        #pragma unroll
        for (int t2 = 0; t2 < 4; ++t2) {
            const int n = nh * 64 + t2 * 16 + am;
            const short* rowp = &Ut[32768 + n * D_DIM];
            #pragma unroll
            for (int kk = 0; kk < 4; ++kk)
                acch[t2] = __builtin_amdgcn_mfma_f32_16x16x32_bf16(
                    ap[kk], *(const short8*)(rowp + pswz[kk]), acch[t2], 0, 0, 0);
        }

        // ---- epilogue 2: h_tilde, h_new, store ----
        #pragma unroll
        for (int t2 = 0; t2 < 4; ++t2) {
            const int c = nh * 64 + t2 * 16 + am;
            const float wh = Wl[2][c], bhv = Wl[5][c];
            #pragma unroll
            for (int pp = 0; pp < 4; ++pp) {
                const int rl = r0 + aq * 4 + pp;
                float ht = tanhf_fast(acch[t2][pp] + Xv[pp] * wh + bhv);
                float zv = zr[t2][pp];
                float hn = zv * hgc[t2][pp] + (1.0f - zv) * ht;
                size_t o = (size_t)(R + rl) * (I_SIZE * D_DIM) + group * D_DIM + c;
                out[o]        = hn;
                out[HOFF + o] = ht;
            }
        }
        __syncthreads();   // hgb reused next pass
    }
}

extern "C" void kernel_launch(void* const* d_in, const int* in_sizes, int n_in,
                              void* d_out, int out_size, void* d_ws, size_t ws_size,
                              hipStream_t stream) {
    const float* X  = (const float*)d_in[0];
    const float* H  = (const float*)d_in[1];
    const float* Wr = (const float*)d_in[2];
    const float* Wz = (const float*)d_in[3];
    const float* Wh = (const float*)d_in[4];
    const float* Ur = (const float*)d_in[5];
    const float* Uz = (const float*)d_in[6];
    const float* Uh = (const float*)d_in[7];
    const float* br = (const float*)d_in[8];
    const float* bz = (const float*)d_in[9];
    const float* bh = (const float*)d_in[10];

    // Workspace intentionally UNUSED: avoids the harness's per-iteration
    // 1-GiB ws re-poison fills landing in the timed stream, and removes the
    // 25 MB ws round-trip + extra launch of the previous 2-kernel design.
    (void)d_ws; (void)ws_size;

    gru_fused<<<dim3(I_SIZE), dim3(1024), 0, stream>>>(
        X, H, Wr, Wz, Wh, Ur, Uz, Uh, br, bz, bh, (float*)d_out);
}

// Round 2
// 430.665 us; speedup vs baseline: 1.1021x; 1.0733x over previous
//
#include <hip/hip_runtime.h>
#include <hip/hip_bf16.h>
#include <stdint.h>

#define I_SIZE 256
#define D_DIM 128
#define BATCH 1024

typedef __attribute__((ext_vector_type(8))) short short8;
typedef __attribute__((ext_vector_type(4))) short short4v;
typedef __attribute__((ext_vector_type(4))) float floatx4;

__device__ inline short f2bf(float f) {
    union { float f; uint32_t u; } v; v.f = f;
    uint32_t u = v.u;
    uint32_t r = (u + 0x7FFFu + ((u >> 16) & 1u)) >> 16;   // RNE
    return (short)(r & 0xFFFFu);
}
__device__ inline float bf2f(short s) {
    union { uint32_t u; float f; } v; v.u = ((uint32_t)(uint16_t)s) << 16;
    return v.f;
}
__device__ inline uint32_t pkbf(float a, float b) {
    __hip_bfloat162 h = __float22bfloat162_rn(make_float2(a, b));
    union { __hip_bfloat162 h; uint32_t u; } v; v.h = h; return v.u;
}
__device__ inline float sigmoidf_fast(float x) { return 1.0f / (1.0f + __expf(-x)); }
__device__ inline float tanhf_fast(float x)    { return 2.0f / (1.0f + __expf(-2.0f * x)) - 1.0f; }

// LDS-only barrier: waits for this wave's LDS ops, does NOT drain vmcnt.
// Global stores keep draining in the background across the barrier (the
// __syncthreads() vmcnt(0) drain was ~25% of kernel time). Single asm block
// so no memory op can be scheduled between the wait and the barrier.
#define BAR_LGKM() asm volatile("s_waitcnt lgkmcnt(0)\n\ts_barrier" ::: "memory")

// ============================================================================
// Fully fused kernel: 256 blocks (1 per group, 1 per CU), 1024 threads
// (16 waves, 4/SIMD). No workspace. U fp32->bf16 transpose in prologue,
// XOR-swizzled LDS image (elem j of U^T row n=k at k*128+p*8+(j&7),
// p=(j>>3)^(k&7)) matching the pswz B-fragment reads.
// Pipelining: H-tile for pass+1 is loaded to registers early in pass
// (hides under r/z+h GEMMs), written to LDS after an lgkm-only barrier.
// ============================================================================
#define S_H 136   // hgb stride in shorts: rows 16B-aligned, A-frag b128 conflict-free

__global__ __launch_bounds__(1024, 4) void gru_fused(
    const float* __restrict__ X, const float* __restrict__ H,
    const float* __restrict__ Wr, const float* __restrict__ Wz, const float* __restrict__ Wh,
    const float* __restrict__ Ur, const float* __restrict__ Uz, const float* __restrict__ Uh,
    const float* __restrict__ br, const float* __restrict__ bz, const float* __restrict__ bh,
    float* __restrict__ out)
{
    __shared__ short Ut[3 * D_DIM * D_DIM];   // 98304 B swizzled bf16 U^T (r,z,h)
    __shared__ short hgb[D_DIM * S_H];        // 34816 B hg tile (later p = r*hg)
    __shared__ float Wl[6][D_DIM];            // 3072 B
    __shared__ float Xl[BATCH];               // 4096 B: X[:, group] staged once

    const int tid   = threadIdx.x;
    const int group = blockIdx.x;
    const int lane  = tid & 63;
    const int w     = tid >> 6;

    if (tid < D_DIM) {
        Wl[0][tid] = Wr[group * D_DIM + tid];
        Wl[1][tid] = Wz[group * D_DIM + tid];
        Wl[2][tid] = Wh[group * D_DIM + tid];
        Wl[3][tid] = br[group * D_DIM + tid];
        Wl[4][tid] = bz[group * D_DIM + tid];
        Wl[5][tid] = bh[group * D_DIM + tid];
    }
    // X column for this group: 4 KB, staged once (was 32k scattered global
    // loads over the kernel; now broadcast ds_reads in the epilogues).
    Xl[tid] = X[(size_t)tid * I_SIZE + group];

    // ---- fused U transpose: global fp32 (coalesced row reads) -> LDS bf16,
    //      transposed + XOR-swizzled. 196 KB/block, once. ----
    {
        const int kc = tid & 127;          // column k of U (contig across lanes)
        const int jb = tid >> 7;           // 0..7
        #pragma unroll
        for (int g = 0; g < 3; ++g) {
            const float* Ug = ((g == 0) ? Ur : (g == 1) ? Uz : Uh)
                              + (size_t)group * (D_DIM * D_DIM);
            short* dst = &Ut[g * (D_DIM * D_DIM)];
            #pragma unroll
            for (int m = 0; m < 4; ++m) {
                const int j0 = m * 8 + jb;                  // 0..31 (j-quad)
                float a0 = Ug[(4 * j0 + 0) * D_DIM + kc];
                float a1 = Ug[(4 * j0 + 1) * D_DIM + kc];
                float a2 = Ug[(4 * j0 + 2) * D_DIM + kc];
                float a3 = Ug[(4 * j0 + 3) * D_DIM + kc];
                short4v s; s.x = f2bf(a0); s.y = f2bf(a1); s.z = f2bf(a2); s.w = f2bf(a3);
                const int p = (j0 >> 1) ^ (kc & 7);
                *(short4v*)&dst[kc * D_DIM + p * 8 + 4 * (j0 & 1)] = s;  // b64 write
            }
        }
    }

    const int srow = tid >> 3;           // staging row 0..127
    const int scol = (tid & 7) * 4;      // staging col base

    // ---- stage pass-0 hg rows -> LDS bf16 ----
    #pragma unroll
    for (int it = 0; it < 4; ++it) {
        int col = scol + it * 32;
        float4 v = *(const float4*)(H + (size_t)srow * (I_SIZE * D_DIM)
                                    + group * D_DIM + col);
        uint2 uu; uu.x = pkbf(v.x, v.y); uu.y = pkbf(v.z, v.w);
        *(uint2*)&hgb[srow * S_H + col] = uu;
    }
    BAR_LGKM();   // barrier A for pass 0

    const int am = lane & 15;
    const int aq = lane >> 4;
    const int rg = w >> 1;           // row group 0..7
    const int nh = w & 1;            // n-half
    const int r0 = rg * 16;
    const size_t HOFF = (size_t)BATCH * I_SIZE * D_DIM;

    int pswz[4];
    #pragma unroll
    for (int kk = 0; kk < 4; ++kk) pswz[kk] = ((4 * kk + aq) ^ (am & 7)) * 8;

    const floatx4 zero = {0.f, 0.f, 0.f, 0.f};

    for (int pass = 0; pass < 8; ++pass) {
        const int R = pass * 128;

        // ---- A fragments (hg) ----
        short8 a[4];
        #pragma unroll
        for (int kk = 0; kk < 4; ++kk)
            a[kk] = *(const short8*)&hgb[(r0 + am) * S_H + kk * 32 + aq * 8];

        // ---- async-STAGE: issue next-pass H loads now; latency hides under
        //      r/z GEMM + epilogue1 + h GEMM. LDS write happens after the
        //      lgkm-only barrier at the bottom of the pass. ----
        float4 pf[4];
        if (pass < 7) {
            #pragma unroll
            for (int it = 0; it < 4; ++it) {
                int col = scol + it * 32;
                pf[it] = *(const float4*)(H + (size_t)(R + 128 + srow) * (I_SIZE * D_DIM)
                                          + group * D_DIM + col);
            }
        }

        // ---- r and z GEMMs (this wave's 64-col half) ----
        floatx4 accr[4], accz[4];
        #pragma unroll
        for (int t2 = 0; t2 < 4; ++t2) { accr[t2] = zero; accz[t2] = zero; }

        #pragma unroll
        for (int t2 = 0; t2 < 4; ++t2) {
            const int n = nh * 64 + t2 * 16 + am;
            const short* rowp = &Ut[n * D_DIM];
            #pragma unroll
            for (int kk = 0; kk < 4; ++kk)
                accr[t2] = __builtin_amdgcn_mfma_f32_16x16x32_bf16(
                    a[kk], *(const short8*)(rowp + pswz[kk]), accr[t2], 0, 0, 0);
            #pragma unroll
            for (int kk = 0; kk < 4; ++kk)
                accz[t2] = __builtin_amdgcn_mfma_f32_16x16x32_bf16(
                    a[kk], *(const short8*)(rowp + 16384 + pswz[kk]), accz[t2], 0, 0, 0);
        }

        // ---- epilogue 1: r,z gates; p = r*hg in place ----
        float Xv[4];
        #pragma unroll
        for (int pp = 0; pp < 4; ++pp)
            Xv[pp] = Xl[R + r0 + aq * 4 + pp];     // broadcast ds_read

        float zr[4][4], hgc[4][4];
        #pragma unroll
        for (int t2 = 0; t2 < 4; ++t2) {
            const int c = nh * 64 + t2 * 16 + am;
            const float wr = Wl[0][c], wz = Wl[1][c], brv = Wl[3][c], bzv = Wl[4][c];
            #pragma unroll
            for (int pp = 0; pp < 4; ++pp) {
                const int rl = r0 + aq * 4 + pp;
                float hgv = bf2f(hgb[rl * S_H + c]);
                float rv = sigmoidf_fast(accr[t2][pp] + Xv[pp] * wr + brv);
                float zv = sigmoidf_fast(accz[t2][pp] + Xv[pp] * wz + bzv);
                zr[t2][pp]  = zv;
                hgc[t2][pp] = hgv;
                hgb[rl * S_H + c] = f2bf(rv * hgv);
            }
        }
        BAR_LGKM();   // barrier B: p writes visible before cross-half ap reads

        // ---- h GEMM: A = p = r*hg ----
        short8 ap[4];
        #pragma unroll
        for (int kk = 0; kk < 4; ++kk)
            ap[kk] = *(const short8*)&hgb[(r0 + am) * S_H + kk * 32 + aq * 8];

        floatx4 acch[4];
        #pragma unroll
        for (int t2 = 0; t2 < 4; ++t2) acch[t2] = zero;
        #pragma unroll
        for (int t2 = 0; t2 < 4; ++t2) {
            const int n = nh * 64 + t2 * 16 + am;
            const short* rowp = &Ut[32768 + n * D_DIM];
            #pragma unroll
            for (int kk = 0; kk < 4; ++kk)
                acch[t2] = __builtin_amdgcn_mfma_f32_16x16x32_bf16(
                    ap[kk], *(const short8*)(rowp + pswz[kk]), acch[t2], 0, 0, 0);
        }

        // ---- epilogue 2: h_tilde, h_new, store (stores drain in background) ----
        #pragma unroll
        for (int t2 = 0; t2 < 4; ++t2) {
            const int c = nh * 64 + t2 * 16 + am;
            const float wh = Wl[2][c], bhv = Wl[5][c];
            #pragma unroll
            for (int pp = 0; pp < 4; ++pp) {
                const int rl = r0 + aq * 4 + pp;
                float ht = tanhf_fast(acch[t2][pp] + Xv[pp] * wh + bhv);
                float zv = zr[t2][pp];
                float hn = zv * hgc[t2][pp] + (1.0f - zv) * ht;
                size_t o = (size_t)(R + rl) * (I_SIZE * D_DIM) + group * D_DIM + c;
                out[o]        = hn;
                out[HOFF + o] = ht;
            }
        }

        if (pass < 7) {
            BAR_LGKM();   // barrier C: all waves done reading hgb (lgkm only;
                          // epilogue-2 stores stay in flight)
            // compiler inserts a counted vmcnt wait here for pf[] (loads were
            // issued before the stores, so the wait tolerates them in flight)
            #pragma unroll
            for (int it = 0; it < 4; ++it) {
                int col = scol + it * 32;
                uint2 uu; uu.x = pkbf(pf[it].x, pf[it].y); uu.y = pkbf(pf[it].z, pf[it].w);
                *(uint2*)&hgb[srow * S_H + col] = uu;
            }
            BAR_LGKM();   // barrier A for next pass
        }
    }
}

extern "C" void kernel_launch(void* const* d_in, const int* in_sizes, int n_in,
                              void* d_out, int out_size, void* d_ws, size_t ws_size,
                              hipStream_t stream) {
    const float* X  = (const float*)d_in[0];
    const float* H  = (const float*)d_in[1];
    const float* Wr = (const float*)d_in[2];
    const float* Wz = (const float*)d_in[3];
    const float* Wh = (const float*)d_in[4];
    const float* Ur = (const float*)d_in[5];
    const float* Uz = (const float*)d_in[6];
    const float* Uh = (const float*)d_in[7];
    const float* br = (const float*)d_in[8];
    const float* bz = (const float*)d_in[9];
    const float* bh = (const float*)d_in[10];

    (void)d_ws; (void)ws_size;   // workspace intentionally unused

    gru_fused<<<dim3(I_SIZE), dim3(1024), 0, stream>>>(
        X, H, Wr, Wz, Wh, Ur, Uz, Uh, br, bz, bh, (float*)d_out);
}